// Round 5
// baseline (539.215 us; speedup 1.0000x reference)
//
#include <hip/hip_runtime.h>
#include <hip/hip_cooperative_groups.h>

namespace cg = cooperative_groups;

// Problem constants
constexpr int cN0 = 819200, cN1 = 81920, cN2 = 8192;
constexpr int cE1 = 819200, cE2 = 81920;
constexpr int cDIN = 128, cDH = 256, cDOUT = 128;
constexpr int cNOFF = cN1 + cN2;               // 90112 = 352 * 256
constexpr int cNBLK = 352;                      // coop grid

typedef __attribute__((ext_vector_type(8))) short bf16x8;
typedef __attribute__((ext_vector_type(4))) float f32x4;
typedef __attribute__((ext_vector_type(8))) unsigned short u16x8;

__device__ __forceinline__ unsigned short f2bf(float f) {
    unsigned u = __builtin_bit_cast(unsigned, f);
    u += 0x7FFF + ((u >> 16) & 1);            // RNE
    return (unsigned short)(u >> 16);
}
__device__ __forceinline__ float bf2f(unsigned short s) {
    unsigned u = ((unsigned)s) << 16;
    return __builtin_bit_cast(float, u);
}

#define GLOAD_LDS16(g, l) __builtin_amdgcn_global_load_lds(               \
    (const __attribute__((address_space(1))) void*)(g),                   \
    (__attribute__((address_space(3))) void*)(l), 16, 0, 0)

// ---------------------------------------------------------------------------
// Cooperative CSR + prep kernel. Grid MUST be 352 x 256.
// Phases: zero offs | hist | per-block partial | scan partials (blk 0) |
//         final scan | build eidx | convert xb + weights.
// ---------------------------------------------------------------------------
__global__ __launch_bounds__(256) void csr_coop_k(
    int* __restrict__ offs, int* __restrict__ part,
    const int* __restrict__ dst1, const int* __restrict__ dst2,
    const int* __restrict__ src1, const int* __restrict__ src2,
    int* __restrict__ eidx1, int* __restrict__ eidx2,
    const float* __restrict__ x, unsigned short* __restrict__ xb,
    const float* __restrict__ w1l, const float* __restrict__ w1r,
    const float* __restrict__ w2l, const float* __restrict__ w2r,
    unsigned short* __restrict__ W1c, unsigned short* __restrict__ W2c)
{
    cg::grid_group grid = cg::this_grid();
    const int tid = threadIdx.x, bid = blockIdx.x;
    const int lane = tid & 63, wid = tid >> 6;
    const int gtid = bid * 256 + tid;            // 0..90111
    __shared__ int ws4[4];
    __shared__ int carry;

    // phase 0: zero offs
    offs[gtid] = 0;
    __threadfence();
    grid.sync();

    // phase 1: fused histogram (10 grid-stride iters)
    for (int e = gtid; e < cE1 + cE2; e += cNOFF) {
        if (e < cE1) atomicAdd(&offs[dst1[e]], 1);
        else atomicAdd(&offs[cN1 + dst2[e - cE1]], 1);
    }
    __threadfence();
    grid.sync();

    // phase 2: per-block partial sum (256 entries per block)
    {
        int v = offs[gtid];
        #pragma unroll
        for (int off = 32; off; off >>= 1) v += __shfl_xor(v, off);
        if (lane == 0) ws4[wid] = v;
        __syncthreads();
        if (tid == 0) part[bid] = ws4[0] + ws4[1] + ws4[2] + ws4[3];
    }
    __threadfence();
    grid.sync();

    // phase 3: block 0 scans part[352] exclusively (2 chunks of 256)
    if (bid == 0) {
        if (tid == 0) carry = 0;
        __syncthreads();
        for (int base = 0; base < cNBLK; base += 256) {
            const int i = base + tid;
            int v = (i < cNBLK) ? part[i] : 0;
            int incl = v;
            #pragma unroll
            for (int off = 1; off < 64; off <<= 1) {
                int t = __shfl_up(incl, off, 64);
                if (lane >= off) incl += t;
            }
            if (lane == 63) ws4[wid] = incl;
            __syncthreads();                      // (A)
            int wpre = 0;
            #pragma unroll
            for (int w = 0; w < 3; ++w) if (w < wid) wpre += ws4[w];
            int c = carry;
            if (i < cNBLK) part[i] = c + wpre + incl - v;   // exclusive
            __syncthreads();                      // (B)
            if (tid == 255) carry = c + wpre + incl;
            __syncthreads();
        }
        __threadfence();
    }
    grid.sync();

    // phase 4: final per-block scan -> exclusive offsets (layer-2 localized)
    {
        int v = offs[gtid];
        int incl = v;
        #pragma unroll
        for (int off = 1; off < 64; off <<= 1) {
            int t = __shfl_up(incl, off, 64);
            if (lane >= off) incl += t;
        }
        if (lane == 63) ws4[wid] = incl;
        __syncthreads();
        int pre = 0;
        #pragma unroll
        for (int w = 0; w < 3; ++w) if (w < wid) pre += ws4[w];
        int r = part[bid] + pre + incl - v;
        if (gtid >= cN1) r -= cE1;
        offs[gtid] = r;
    }
    __threadfence();
    grid.sync();

    // phase 5: build (cursor -> end offsets afterwards)
    for (int e = gtid; e < cE1 + cE2; e += cNOFF) {
        if (e < cE1) {
            int p = atomicAdd(&offs[dst1[e]], 1);
            eidx1[p] = src1[e];
        } else {
            int e2 = e - cE1;
            int p = atomicAdd(&offs[cN1 + dst2[e2]], 1);
            eidx2[p] = src2[e2];
        }
    }

    // phase 6: conversions (consumed only after kernel end; no sync needed)
    // 6a: xb = bf16(x[:N1])  (1,310,720 vec8 ops)
    for (int i = gtid; i < cN1 * cDIN / 8; i += cNOFF) {
        const float* p = x + (size_t)i * 8;
        float4 a = *reinterpret_cast<const float4*>(p);
        float4 b = *reinterpret_cast<const float4*>(p + 4);
        u16x8 o;
        o[0] = f2bf(a.x); o[1] = f2bf(a.y); o[2] = f2bf(a.z); o[3] = f2bf(a.w);
        o[4] = f2bf(b.x); o[5] = f2bf(b.y); o[6] = f2bf(b.z); o[7] = f2bf(b.w);
        reinterpret_cast<u16x8*>(xb)[i] = o;
    }
    // 6b: weights -> bf16 W^T concat
    for (int t = gtid; t < 256 * 256 + 128 * 512; t += cNOFF) {
        if (t < 256 * 256) {
            int n = t >> 8, k = t & 255;
            float v = (k < 128) ? w1l[k * 256 + n] : w1r[(k - 128) * 256 + n];
            W1c[n * 256 + k] = f2bf(v);
        } else {
            int t2 = t - 256 * 256;
            int n = t2 >> 9, k = t2 & 511;
            float v = (k < 256) ? w2l[k * 128 + n] : w2r[(k - 256) * 128 + n];
            W2c[n * 512 + k] = f2bf(v);
        }
    }
}

// ---------------------------------------------------------------------------
// Layer-1 aggregate: one wave per dst row, 16-lane group per edge.
// ---------------------------------------------------------------------------
__global__ __launch_bounds__(256) void agg1_k(
    const float* __restrict__ x, const int* __restrict__ cursor,
    const int* __restrict__ eidx, unsigned short* __restrict__ mean1)
{
    const int row = blockIdx.x * 4 + (threadIdx.x >> 6);
    const int lane = threadIdx.x & 63;
    const int g = lane >> 4, li = lane & 15;
    const int start = row ? cursor[row - 1] : 0;
    const int end = cursor[row];
    float acc[8] = {};
    for (int e = start + g; e < end; e += 4) {
        const int s = eidx[e];
        const float4* p = reinterpret_cast<const float4*>(x + (size_t)s * cDIN + li * 8);
        float4 a = p[0], b = p[1];
        acc[0] += a.x; acc[1] += a.y; acc[2] += a.z; acc[3] += a.w;
        acc[4] += b.x; acc[5] += b.y; acc[6] += b.z; acc[7] += b.w;
    }
    #pragma unroll
    for (int i = 0; i < 8; ++i) {
        acc[i] += __shfl_xor(acc[i], 16);
        acc[i] += __shfl_xor(acc[i], 32);
    }
    if (g == 0) {
        const float inv = 1.0f / fmaxf((float)(end - start), 1.0f);
        u16x8 o;
        #pragma unroll
        for (int i = 0; i < 8; ++i) o[i] = f2bf(acc[i] * inv);
        *reinterpret_cast<u16x8*>(mean1 + (size_t)row * cDIN + li * 8) = o;
    }
}

// ---------------------------------------------------------------------------
// Layer-2 aggregate: gather bf16 h rows; mean2 bf16.
// ---------------------------------------------------------------------------
__global__ __launch_bounds__(256) void agg2_k(
    const unsigned short* __restrict__ h, const int* __restrict__ cursor,
    const int* __restrict__ eidx, unsigned short* __restrict__ mean2)
{
    const int row = blockIdx.x * 4 + (threadIdx.x >> 6);
    const int lane = threadIdx.x & 63;
    const int g = lane >> 4, li = lane & 15;
    const int start = row ? cursor[row - 1] : 0;
    const int end = cursor[row];
    float acc[16] = {};
    for (int e = start + g; e < end; e += 4) {
        const int s = eidx[e];
        const u16x8* p = reinterpret_cast<const u16x8*>(h + (size_t)s * cDH + li * 16);
        u16x8 a = p[0], b = p[1];
        #pragma unroll
        for (int i = 0; i < 8; ++i) { acc[i] += bf2f(a[i]); acc[8 + i] += bf2f(b[i]); }
    }
    #pragma unroll
    for (int i = 0; i < 16; ++i) {
        acc[i] += __shfl_xor(acc[i], 16);
        acc[i] += __shfl_xor(acc[i], 32);
    }
    if (g == 0) {
        const float inv = 1.0f / fmaxf((float)(end - start), 1.0f);
        u16x8 o0, o1;
        #pragma unroll
        for (int i = 0; i < 8; ++i) { o0[i] = f2bf(acc[i] * inv); o1[i] = f2bf(acc[8 + i] * inv); }
        u16x8* q = reinterpret_cast<u16x8*>(mean2 + (size_t)row * cDH + li * 16);
        q[0] = o0; q[1] = o1;
    }
}

// ---------------------------------------------------------------------------
// Layer-1 GEMM, m97-style: global_load_lds(16B) staging, linear LDS,
// 128x128 tile, 4 waves 2x2, K=256 split as [mean1 | xb].
// h = relu([mean1 | xb] @ W1c^T + b1), bf16 store.
// ---------------------------------------------------------------------------
__global__ __launch_bounds__(256) void gemm1_k(
    const unsigned short* __restrict__ mean1,   // [N1][128] bf16
    const unsigned short* __restrict__ xb,      // [N1][128] bf16
    const unsigned short* __restrict__ W1c,     // [256][256] bf16 (n-major)
    const float* __restrict__ b1,
    unsigned short* __restrict__ h)             // [N1][256] bf16
{
    __shared__ unsigned short As[128 * 32];     // 8 KB, linear [r][32]
    __shared__ unsigned short Bs[128 * 32];

    const int tid = threadIdx.x;
    const int l = tid & 63, w = tid >> 6;
    const int q = l >> 4, r16 = l & 15;
    const int wr0 = (w >> 1) * 64, wc0 = (w & 1) * 64;
    const int n0 = blockIdx.x * 128, row0 = blockIdx.y * 128;

    // staging: wave w stages rows [32w, 32w+32) via 2 x (64 lanes x 16 B)
    const int srow = w * 32 + (l >> 2);          // row for chunk j=0
    const int skoff = (l & 3) * 8;               // k element offset

    const f32x4 zero = {0.f, 0.f, 0.f, 0.f};
    f32x4 acc[4][4];
    #pragma unroll
    for (int m = 0; m < 4; ++m)
        #pragma unroll
        for (int n = 0; n < 4; ++n) acc[m][n] = zero;

    for (int k0 = 0; k0 < 256; k0 += 32) {
        const unsigned short* Asrc = (k0 < 128) ? mean1 : xb;
        const int kk = k0 & 127;
        __syncthreads();                         // prior LDS reads done
        #pragma unroll
        for (int j = 0; j < 2; ++j) {
            const int r = srow + j * 16;
            GLOAD_LDS16(Asrc + (size_t)(row0 + r) * 128 + kk + skoff,
                        As + (w * 2 + j) * 512);
            GLOAD_LDS16(W1c + (size_t)(n0 + r) * 256 + k0 + skoff,
                        Bs + (w * 2 + j) * 512);
        }
        __syncthreads();                         // vmcnt drained before barrier
        bf16x8 af[4], bg[4];
        #pragma unroll
        for (int m = 0; m < 4; ++m)
            af[m] = *reinterpret_cast<const bf16x8*>(As + (wr0 + 16 * m + r16) * 32 + q * 8);
        #pragma unroll
        for (int n = 0; n < 4; ++n)
            bg[n] = *reinterpret_cast<const bf16x8*>(Bs + (wc0 + 16 * n + r16) * 32 + q * 8);
        #pragma unroll
        for (int m = 0; m < 4; ++m)
            #pragma unroll
            for (int n = 0; n < 4; ++n)
                acc[m][n] = __builtin_amdgcn_mfma_f32_16x16x32_bf16(af[m], bg[n], acc[m][n], 0, 0, 0);
    }

    // epilogue — D layout: col = lane&15, row = 4*(lane>>4) + reg
    #pragma unroll
    for (int n = 0; n < 4; ++n) {
        const int col = n0 + wc0 + 16 * n + r16;
        const float bv = b1[col];
        #pragma unroll
        for (int m = 0; m < 4; ++m) {
            #pragma unroll
            for (int j = 0; j < 4; ++j) {
                const int row = row0 + wr0 + 16 * m + 4 * q + j;
                h[(size_t)row * cDH + col] = f2bf(fmaxf(acc[m][n][j] + bv, 0.f));
            }
        }
    }
}

// ---------------------------------------------------------------------------
// Layer-2 GEMM (reg-staged, padded LDS): out = [mean2 | h] @ W2c^T + b2.
// K=512, N=128, TM=64: 4 waves 1x4 (64x32 each).
// ---------------------------------------------------------------------------
__global__ __launch_bounds__(256) void gemm2_k(
    const unsigned short* __restrict__ mean2,   // [N2][256]
    const unsigned short* __restrict__ hd,      // [N2][256] (h top rows)
    const unsigned short* __restrict__ W2c,     // [128][512]
    const float* __restrict__ b2, float* __restrict__ out)
{
    constexpr int K = 512, KL = 256, N = 128, TM = 64;
    constexpr int LD = 40;
    __shared__ unsigned short As[TM * LD];
    __shared__ unsigned short Bs[128 * LD];

    const int tid = threadIdx.x;
    const int l = tid & 63, w = tid >> 6;
    const int q = l >> 4, r16 = l & 15;
    const int wc0 = w * 32;
    const int row0 = blockIdx.y * TM;

    const f32x4 zero = {0.f, 0.f, 0.f, 0.f};
    f32x4 acc[4][2];
    #pragma unroll
    for (int m = 0; m < 4; ++m) { acc[m][0] = zero; acc[m][1] = zero; }

    for (int k0 = 0; k0 < K; k0 += 32) {
        const bool left = (k0 < KL);
        const unsigned short* Asrc = left ? mean2 : hd;
        const int kk = k0 & (KL - 1);
        __syncthreads();
        {   // A tile: 64 rows x 32 k = 256 slots of 16 B
            int r = tid >> 2, o16 = tid & 3;
            bf16x8 av = *reinterpret_cast<const bf16x8*>(Asrc + (size_t)(row0 + r) * KL + kk + o16 * 8);
            *reinterpret_cast<bf16x8*>(As + r * LD + o16 * 8) = av;
        }
        #pragma unroll
        for (int c = 0; c < 2; ++c) {   // B tile: 128 rows -> 512 slots
            int z = tid + c * 256;
            int r = z >> 2, o16 = z & 3;
            bf16x8 bv = *reinterpret_cast<const bf16x8*>(W2c + (size_t)r * K + k0 + o16 * 8);
            *reinterpret_cast<bf16x8*>(Bs + r * LD + o16 * 8) = bv;
        }
        __syncthreads();
        bf16x8 af[4], bg[2];
        #pragma unroll
        for (int m = 0; m < 4; ++m)
            af[m] = *reinterpret_cast<const bf16x8*>(As + (16 * m + r16) * LD + q * 8);
        #pragma unroll
        for (int n = 0; n < 2; ++n)
            bg[n] = *reinterpret_cast<const bf16x8*>(Bs + (wc0 + 16 * n + r16) * LD + q * 8);
        #pragma unroll
        for (int m = 0; m < 4; ++m)
            #pragma unroll
            for (int n = 0; n < 2; ++n)
                acc[m][n] = __builtin_amdgcn_mfma_f32_16x16x32_bf16(af[m], bg[n], acc[m][n], 0, 0, 0);
    }

    #pragma unroll
    for (int n = 0; n < 2; ++n) {
        const int col = wc0 + 16 * n + r16;
        const float bv = b2[col];
        #pragma unroll
        for (int m = 0; m < 4; ++m) {
            #pragma unroll
            for (int j = 0; j < 4; ++j) {
                const int row = row0 + 16 * m + 4 * q + j;
                out[(size_t)row * N + col] = acc[m][n][j] + bv;
            }
        }
    }
}

// ---------------------------------------------------------------------------
extern "C" void kernel_launch(void* const* d_in, const int* in_sizes, int n_in,
                              void* d_out, int out_size, void* d_ws, size_t ws_size,
                              hipStream_t stream)
{
    const float* x    = (const float*)d_in[0];
    const int*   src1 = (const int*)d_in[1];
    const int*   dst1 = (const int*)d_in[2];
    const int*   src2 = (const int*)d_in[3];
    const int*   dst2 = (const int*)d_in[4];
    const float* w1l  = (const float*)d_in[7];
    const float* b1   = (const float*)d_in[8];
    const float* w1r  = (const float*)d_in[9];
    const float* w2l  = (const float*)d_in[10];
    const float* b2   = (const float*)d_in[11];
    const float* w2r  = (const float*)d_in[12];
    float* out = (float*)d_out;

    // Workspace (~92.4 MB):
    unsigned short* mean1 = (unsigned short*)d_ws;        // [81920][128]
    unsigned short* h     = mean1 + (size_t)cN1 * cDIN;   // [81920][256]
    unsigned short* mean2 = h + (size_t)cN1 * cDH;        // [8192][256]
    unsigned short* W1c   = mean2 + (size_t)cN2 * cDH;    // [256][256]
    unsigned short* W2c   = W1c + 256 * 256;              // [128][512]
    unsigned short* xb    = W2c + 128 * 512;              // [81920][128]
    int* offs  = (int*)(xb + (size_t)cN1 * cDIN);         // [90112]
    int* eidx1 = offs + cNOFF;                            // [819200]
    int* eidx2 = eidx1 + cE1;                             // [81920]
    int* part  = eidx2 + cE2;                             // [352]

    // 1. cooperative CSR + prep
    {
        void* args[] = {
            (void*)&offs, (void*)&part,
            (void*)&dst1, (void*)&dst2, (void*)&src1, (void*)&src2,
            (void*)&eidx1, (void*)&eidx2,
            (void*)&x, (void*)&xb,
            (void*)&w1l, (void*)&w1r, (void*)&w2l, (void*)&w2r,
            (void*)&W1c, (void*)&W2c
        };
        hipLaunchCooperativeKernel((void*)csr_coop_k, dim3(cNBLK), dim3(256),
                                   args, 0, stream);
    }
    // 2. layer-1 aggregate
    agg1_k<<<cN1 / 4, 256, 0, stream>>>(x, offs, eidx1, mean1);
    // 3. layer-1 GEMM
    gemm1_k<<<dim3(2, cN1 / 128), 256, 0, stream>>>(mean1, xb, W1c, b1, h);
    // 4. layer-2 aggregate
    agg2_k<<<cN2 / 4, 256, 0, stream>>>(h, offs + cN1, eidx2, mean2);
    // 5. layer-2 GEMM
    gemm2_k<<<dim3(1, cN2 / 64), 256, 0, stream>>>(mean2, h, W2c, b2, out);
}

// Round 6
// 246.113 us; speedup vs baseline: 2.1909x; 2.1909x over previous
//
#include <hip/hip_runtime.h>

// Problem constants
constexpr int cN0 = 819200, cN1 = 81920, cN2 = 8192;
constexpr int cE1 = 819200, cE2 = 81920;
constexpr int cDIN = 128, cDH = 256, cDOUT = 128;
constexpr int cNOFF = cN1 + cN2;               // 90112 = 88 * 1024

typedef __attribute__((ext_vector_type(8))) short bf16x8;
typedef __attribute__((ext_vector_type(4))) float f32x4;
typedef __attribute__((ext_vector_type(8))) unsigned short u16x8;

__device__ __forceinline__ unsigned short f2bf(float f) {
    unsigned u = __builtin_bit_cast(unsigned, f);
    u += 0x7FFF + ((u >> 16) & 1);            // RNE
    return (unsigned short)(u >> 16);
}
__device__ __forceinline__ float bf2f(unsigned short s) {
    unsigned u = ((unsigned)s) << 16;
    return __builtin_bit_cast(float, u);
}

#define GLOAD_LDS16(g, l) __builtin_amdgcn_global_load_lds(               \
    (const __attribute__((address_space(1))) void*)(g),                   \
    (__attribute__((address_space(3))) void*)(l), 16, 0, 0)

// ---------------------------------------------------------------------------
// setup: zero offs + weights -> bf16 W^T concat + xb = bf16(x[:N1]).
// Flat index over 90112 + 196608 + 1310720 items = 6240 blocks of 256.
// ---------------------------------------------------------------------------
__global__ __launch_bounds__(256) void setup_k(
    int* __restrict__ offs,
    const float* __restrict__ w1l, const float* __restrict__ w1r,
    const float* __restrict__ w2l, const float* __restrict__ w2r,
    unsigned short* __restrict__ W1c, unsigned short* __restrict__ W2c,
    const float* __restrict__ x, unsigned short* __restrict__ xb)
{
    int id = blockIdx.x * 256 + threadIdx.x;
    if (id < cNOFF) { offs[id] = 0; return; }
    id -= cNOFF;
    if (id < 256 * 256) {
        int n = id >> 8, k = id & 255;
        float v = (k < 128) ? w1l[k * 256 + n] : w1r[(k - 128) * 256 + n];
        W1c[n * 256 + k] = f2bf(v);
        return;
    }
    id -= 256 * 256;
    if (id < 128 * 512) {
        int n = id >> 9, k = id & 511;
        float v = (k < 256) ? w2l[k * 128 + n] : w2r[(k - 256) * 128 + n];
        W2c[n * 512 + k] = f2bf(v);
        return;
    }
    id -= 128 * 512;
    // xb conversion: one vec8 per thread
    {
        const float* p = x + (size_t)id * 8;
        float4 a = *reinterpret_cast<const float4*>(p);
        float4 b = *reinterpret_cast<const float4*>(p + 4);
        u16x8 o;
        o[0] = f2bf(a.x); o[1] = f2bf(a.y); o[2] = f2bf(a.z); o[3] = f2bf(a.w);
        o[4] = f2bf(b.x); o[5] = f2bf(b.y); o[6] = f2bf(b.z); o[7] = f2bf(b.w);
        reinterpret_cast<u16x8*>(xb)[id] = o;
    }
}

// ---------------------------------------------------------------------------
// fused histogram over both edge lists
// ---------------------------------------------------------------------------
__global__ __launch_bounds__(256) void hist_k(
    const int* __restrict__ dst1, const int* __restrict__ dst2,
    int* __restrict__ offs)
{
    int e = blockIdx.x * 256 + threadIdx.x;
    if (e < cE1) atomicAdd(&offs[dst1[e]], 1);
    else {
        int e2 = e - cE1;
        if (e2 < cE2) atomicAdd(&offs[cN1 + dst2[e2]], 1);
    }
}

// ---------------------------------------------------------------------------
// hierarchical exclusive scan over offs[90112] (88 blocks of 1024)
// ---------------------------------------------------------------------------
__global__ __launch_bounds__(1024) void partial_k(
    const int* __restrict__ a, int* __restrict__ part)
{
    const int tid = threadIdx.x, lane = tid & 63, wid = tid >> 6;
    int v = a[blockIdx.x * 1024 + tid];
    #pragma unroll
    for (int off = 32; off; off >>= 1) v += __shfl_xor(v, off);
    __shared__ int ws[16];
    if (lane == 0) ws[wid] = v;
    __syncthreads();
    if (tid == 0) {
        int s = 0;
        #pragma unroll
        for (int i = 0; i < 16; ++i) s += ws[i];
        part[blockIdx.x] = s;
    }
}

__global__ __launch_bounds__(128) void scanp_k(int* __restrict__ part) // n=88
{
    const int tid = threadIdx.x, lane = tid & 63, wid = tid >> 6;
    int v = (tid < 88) ? part[tid] : 0;
    int incl = v;
    #pragma unroll
    for (int off = 1; off < 64; off <<= 1) {
        int t = __shfl_up(incl, off, 64);
        if (lane >= off) incl += t;
    }
    __shared__ int w0;
    if (wid == 0 && lane == 63) w0 = incl;
    __syncthreads();
    int pre = wid ? w0 : 0;
    if (tid < 88) part[tid] = pre + incl - v;   // exclusive
}

__global__ __launch_bounds__(1024) void final_k(
    int* __restrict__ a, const int* __restrict__ part)
{
    const int tid = threadIdx.x, lane = tid & 63, wid = tid >> 6;
    const int g = blockIdx.x * 1024 + tid;
    int v = a[g];
    int incl = v;
    #pragma unroll
    for (int off = 1; off < 64; off <<= 1) {
        int t = __shfl_up(incl, off, 64);
        if (lane >= off) incl += t;
    }
    __shared__ int ws[16];
    if (lane == 63) ws[wid] = incl;
    __syncthreads();
    int pre = 0;
    #pragma unroll
    for (int i = 0; i < 16; ++i) if (i < wid) pre += ws[i];
    int r = part[blockIdx.x] + pre + incl - v;          // global exclusive
    if (g >= cN1) r -= cE1;                              // layer-2 local
    a[g] = r;
}

// ---------------------------------------------------------------------------
// fused CSR permute for both layers (cursor -> end offsets afterwards)
// ---------------------------------------------------------------------------
__global__ __launch_bounds__(256) void build_k(
    const int* __restrict__ src1, const int* __restrict__ dst1,
    const int* __restrict__ src2, const int* __restrict__ dst2,
    int* __restrict__ offs, int* __restrict__ eidx1, int* __restrict__ eidx2)
{
    int e = blockIdx.x * 256 + threadIdx.x;
    if (e < cE1) {
        int p = atomicAdd(&offs[dst1[e]], 1);
        eidx1[p] = src1[e];
    } else {
        int e2 = e - cE1;
        if (e2 < cE2) {
            int p = atomicAdd(&offs[cN1 + dst2[e2]], 1);
            eidx2[p] = src2[e2];
        }
    }
}

// ---------------------------------------------------------------------------
// Layer-1 aggregate: one wave per dst row, 16-lane group per edge.
// ---------------------------------------------------------------------------
__global__ __launch_bounds__(256) void agg1_k(
    const float* __restrict__ x, const int* __restrict__ cursor,
    const int* __restrict__ eidx, unsigned short* __restrict__ mean1)
{
    const int row = blockIdx.x * 4 + (threadIdx.x >> 6);
    const int lane = threadIdx.x & 63;
    const int g = lane >> 4, li = lane & 15;
    const int start = row ? cursor[row - 1] : 0;
    const int end = cursor[row];
    float acc[8] = {};
    for (int e = start + g; e < end; e += 4) {
        const int s = eidx[e];
        const float4* p = reinterpret_cast<const float4*>(x + (size_t)s * cDIN + li * 8);
        float4 a = p[0], b = p[1];
        acc[0] += a.x; acc[1] += a.y; acc[2] += a.z; acc[3] += a.w;
        acc[4] += b.x; acc[5] += b.y; acc[6] += b.z; acc[7] += b.w;
    }
    #pragma unroll
    for (int i = 0; i < 8; ++i) {
        acc[i] += __shfl_xor(acc[i], 16);
        acc[i] += __shfl_xor(acc[i], 32);
    }
    if (g == 0) {
        const float inv = 1.0f / fmaxf((float)(end - start), 1.0f);
        u16x8 o;
        #pragma unroll
        for (int i = 0; i < 8; ++i) o[i] = f2bf(acc[i] * inv);
        *reinterpret_cast<u16x8*>(mean1 + (size_t)row * cDIN + li * 8) = o;
    }
}

// ---------------------------------------------------------------------------
// Layer-2 aggregate: gather bf16 h rows; mean2 bf16.
// ---------------------------------------------------------------------------
__global__ __launch_bounds__(256) void agg2_k(
    const unsigned short* __restrict__ h, const int* __restrict__ cursor,
    const int* __restrict__ eidx, unsigned short* __restrict__ mean2)
{
    const int row = blockIdx.x * 4 + (threadIdx.x >> 6);
    const int lane = threadIdx.x & 63;
    const int g = lane >> 4, li = lane & 15;
    const int start = row ? cursor[row - 1] : 0;
    const int end = cursor[row];
    float acc[16] = {};
    for (int e = start + g; e < end; e += 4) {
        const int s = eidx[e];
        const u16x8* p = reinterpret_cast<const u16x8*>(h + (size_t)s * cDH + li * 16);
        u16x8 a = p[0], b = p[1];
        #pragma unroll
        for (int i = 0; i < 8; ++i) { acc[i] += bf2f(a[i]); acc[8 + i] += bf2f(b[i]); }
    }
    #pragma unroll
    for (int i = 0; i < 16; ++i) {
        acc[i] += __shfl_xor(acc[i], 16);
        acc[i] += __shfl_xor(acc[i], 32);
    }
    if (g == 0) {
        const float inv = 1.0f / fmaxf((float)(end - start), 1.0f);
        u16x8 o0, o1;
        #pragma unroll
        for (int i = 0; i < 8; ++i) { o0[i] = f2bf(acc[i] * inv); o1[i] = f2bf(acc[8 + i] * inv); }
        u16x8* q = reinterpret_cast<u16x8*>(mean2 + (size_t)row * cDH + li * 16);
        q[0] = o0; q[1] = o1;
    }
}

// ---------------------------------------------------------------------------
// Layer-1 GEMM, m97-style: global_load_lds(16B) staging, linear LDS,
// 128x128 tile, 4 waves 2x2, K=256 split as [mean1 | xb].
// h = relu([mean1 | xb] @ W1c^T + b1), bf16 store.   [verified R5]
// ---------------------------------------------------------------------------
__global__ __launch_bounds__(256) void gemm1_k(
    const unsigned short* __restrict__ mean1,   // [N1][128] bf16
    const unsigned short* __restrict__ xb,      // [N1][128] bf16
    const unsigned short* __restrict__ W1c,     // [256][256] bf16 (n-major)
    const float* __restrict__ b1,
    unsigned short* __restrict__ h)             // [N1][256] bf16
{
    __shared__ unsigned short As[128 * 32];     // 8 KB, linear [r][32]
    __shared__ unsigned short Bs[128 * 32];

    const int tid = threadIdx.x;
    const int l = tid & 63, w = tid >> 6;
    const int q = l >> 4, r16 = l & 15;
    const int wr0 = (w >> 1) * 64, wc0 = (w & 1) * 64;
    const int n0 = blockIdx.x * 128, row0 = blockIdx.y * 128;

    // staging: wave w stages rows [32w, 32w+32) via 2 x (64 lanes x 16 B)
    const int srow = w * 32 + (l >> 2);          // row for chunk j=0
    const int skoff = (l & 3) * 8;               // k element offset

    const f32x4 zero = {0.f, 0.f, 0.f, 0.f};
    f32x4 acc[4][4];
    #pragma unroll
    for (int m = 0; m < 4; ++m)
        #pragma unroll
        for (int n = 0; n < 4; ++n) acc[m][n] = zero;

    for (int k0 = 0; k0 < 256; k0 += 32) {
        const unsigned short* Asrc = (k0 < 128) ? mean1 : xb;
        const int kk = k0 & 127;
        __syncthreads();                         // prior LDS reads done
        #pragma unroll
        for (int j = 0; j < 2; ++j) {
            const int r = srow + j * 16;
            GLOAD_LDS16(Asrc + (size_t)(row0 + r) * 128 + kk + skoff,
                        As + (w * 2 + j) * 512);
            GLOAD_LDS16(W1c + (size_t)(n0 + r) * 256 + k0 + skoff,
                        Bs + (w * 2 + j) * 512);
        }
        __syncthreads();                         // vmcnt drained before barrier
        bf16x8 af[4], bg[4];
        #pragma unroll
        for (int m = 0; m < 4; ++m)
            af[m] = *reinterpret_cast<const bf16x8*>(As + (wr0 + 16 * m + r16) * 32 + q * 8);
        #pragma unroll
        for (int n = 0; n < 4; ++n)
            bg[n] = *reinterpret_cast<const bf16x8*>(Bs + (wc0 + 16 * n + r16) * 32 + q * 8);
        #pragma unroll
        for (int m = 0; m < 4; ++m)
            #pragma unroll
            for (int n = 0; n < 4; ++n)
                acc[m][n] = __builtin_amdgcn_mfma_f32_16x16x32_bf16(af[m], bg[n], acc[m][n], 0, 0, 0);
    }

    // epilogue — D layout: col = lane&15, row = 4*(lane>>4) + reg
    #pragma unroll
    for (int n = 0; n < 4; ++n) {
        const int col = n0 + wc0 + 16 * n + r16;
        const float bv = b1[col];
        #pragma unroll
        for (int m = 0; m < 4; ++m) {
            #pragma unroll
            for (int j = 0; j < 4; ++j) {
                const int row = row0 + wr0 + 16 * m + 4 * q + j;
                h[(size_t)row * cDH + col] = f2bf(fmaxf(acc[m][n][j] + bv, 0.f));
            }
        }
    }
}

// ---------------------------------------------------------------------------
// Layer-2 GEMM (reg-staged, padded LDS): out = [mean2 | h] @ W2c^T + b2.
// K=512, N=128, TM=64: 4 waves 1x4 (64x32 each).   [verified R5]
// ---------------------------------------------------------------------------
__global__ __launch_bounds__(256) void gemm2_k(
    const unsigned short* __restrict__ mean2,   // [N2][256]
    const unsigned short* __restrict__ hd,      // [N2][256] (h top rows)
    const unsigned short* __restrict__ W2c,     // [128][512]
    const float* __restrict__ b2, float* __restrict__ out)
{
    constexpr int K = 512, KL = 256, N = 128, TM = 64;
    constexpr int LD = 40;
    __shared__ unsigned short As[TM * LD];
    __shared__ unsigned short Bs[128 * LD];

    const int tid = threadIdx.x;
    const int l = tid & 63, w = tid >> 6;
    const int q = l >> 4, r16 = l & 15;
    const int wc0 = w * 32;
    const int row0 = blockIdx.y * TM;

    const f32x4 zero = {0.f, 0.f, 0.f, 0.f};
    f32x4 acc[4][2];
    #pragma unroll
    for (int m = 0; m < 4; ++m) { acc[m][0] = zero; acc[m][1] = zero; }

    for (int k0 = 0; k0 < K; k0 += 32) {
        const bool left = (k0 < KL);
        const unsigned short* Asrc = left ? mean2 : hd;
        const int kk = k0 & (KL - 1);
        __syncthreads();
        {   // A tile: 64 rows x 32 k = 256 slots of 16 B
            int r = tid >> 2, o16 = tid & 3;
            bf16x8 av = *reinterpret_cast<const bf16x8*>(Asrc + (size_t)(row0 + r) * KL + kk + o16 * 8);
            *reinterpret_cast<bf16x8*>(As + r * LD + o16 * 8) = av;
        }
        #pragma unroll
        for (int c = 0; c < 2; ++c) {   // B tile: 128 rows -> 512 slots
            int z = tid + c * 256;
            int r = z >> 2, o16 = z & 3;
            bf16x8 bv = *reinterpret_cast<const bf16x8*>(W2c + (size_t)r * K + k0 + o16 * 8);
            *reinterpret_cast<bf16x8*>(Bs + r * LD + o16 * 8) = bv;
        }
        __syncthreads();
        bf16x8 af[4], bg[2];
        #pragma unroll
        for (int m = 0; m < 4; ++m)
            af[m] = *reinterpret_cast<const bf16x8*>(As + (16 * m + r16) * LD + q * 8);
        #pragma unroll
        for (int n = 0; n < 2; ++n)
            bg[n] = *reinterpret_cast<const bf16x8*>(Bs + (wc0 + 16 * n + r16) * LD + q * 8);
        #pragma unroll
        for (int m = 0; m < 4; ++m)
            #pragma unroll
            for (int n = 0; n < 2; ++n)
                acc[m][n] = __builtin_amdgcn_mfma_f32_16x16x32_bf16(af[m], bg[n], acc[m][n], 0, 0, 0);
    }

    #pragma unroll
    for (int n = 0; n < 2; ++n) {
        const int col = wc0 + 16 * n + r16;
        const float bv = b2[col];
        #pragma unroll
        for (int m = 0; m < 4; ++m) {
            #pragma unroll
            for (int j = 0; j < 4; ++j) {
                const int row = row0 + 16 * m + 4 * q + j;
                out[(size_t)row * N + col] = acc[m][n][j] + bv;
            }
        }
    }
}

// ---------------------------------------------------------------------------
extern "C" void kernel_launch(void* const* d_in, const int* in_sizes, int n_in,
                              void* d_out, int out_size, void* d_ws, size_t ws_size,
                              hipStream_t stream)
{
    const float* x    = (const float*)d_in[0];
    const int*   src1 = (const int*)d_in[1];
    const int*   dst1 = (const int*)d_in[2];
    const int*   src2 = (const int*)d_in[3];
    const int*   dst2 = (const int*)d_in[4];
    const float* w1l  = (const float*)d_in[7];
    const float* b1   = (const float*)d_in[8];
    const float* w1r  = (const float*)d_in[9];
    const float* w2l  = (const float*)d_in[10];
    const float* b2   = (const float*)d_in[11];
    const float* w2r  = (const float*)d_in[12];
    float* out = (float*)d_out;

    // Workspace (~92.4 MB):
    unsigned short* mean1 = (unsigned short*)d_ws;        // [81920][128]
    unsigned short* h     = mean1 + (size_t)cN1 * cDIN;   // [81920][256]
    unsigned short* mean2 = h + (size_t)cN1 * cDH;        // [8192][256]
    unsigned short* W1c   = mean2 + (size_t)cN2 * cDH;    // [256][256]
    unsigned short* W2c   = W1c + 256 * 256;              // [128][512]
    unsigned short* xb    = W2c + 128 * 512;              // [81920][128]
    int* offs  = (int*)(xb + (size_t)cN1 * cDIN);         // [90112]
    int* eidx1 = offs + cNOFF;                            // [819200]
    int* eidx2 = eidx1 + cE1;                             // [81920]
    int* part  = eidx2 + cE2;                             // [88]

    // 1. setup: zero offs + weight conv + xb conv (6240 blocks)
    {
        int total = cNOFF + 256 * 256 + 128 * 512 + cN1 * cDIN / 8;  // 1,597,440
        setup_k<<<total / 256, 256, 0, stream>>>(offs, w1l, w1r, w2l, w2r,
                                                 W1c, W2c, x, xb);
    }
    // 2-6. CSR for both layers
    hist_k<<<(cE1 + cE2) / 256, 256, 0, stream>>>(dst1, dst2, offs);
    partial_k<<<cNOFF / 1024, 1024, 0, stream>>>(offs, part);
    scanp_k<<<1, 128, 0, stream>>>(part);
    final_k<<<cNOFF / 1024, 1024, 0, stream>>>(offs, part);
    build_k<<<(cE1 + cE2) / 256, 256, 0, stream>>>(src1, dst1, src2, dst2, offs, eidx1, eidx2);

    // 7. layer-1 aggregate
    agg1_k<<<cN1 / 4, 256, 0, stream>>>(x, offs, eidx1, mean1);
    // 8. layer-1 GEMM
    gemm1_k<<<dim3(2, cN1 / 128), 256, 0, stream>>>(mean1, xb, W1c, b1, h);
    // 9. layer-2 aggregate
    agg2_k<<<cN2 / 4, 256, 0, stream>>>(h, offs + cN1, eidx2, mean2);
    // 10. layer-2 GEMM
    gemm2_k<<<dim3(1, cN2 / 64), 256, 0, stream>>>(mean2, h, W2c, b2, out);
}

// Round 7
// 242.658 us; speedup vs baseline: 2.2221x; 1.0142x over previous
//
#include <hip/hip_runtime.h>

// Problem constants
constexpr int cN0 = 819200, cN1 = 81920, cN2 = 8192;
constexpr int cE1 = 819200, cE2 = 81920;
constexpr int cEtot = cE1 + cE2;               // 901120
constexpr int cDIN = 128, cDH = 256, cDOUT = 128;
constexpr int cNOFF = cN1 + cN2;               // 90112 = 88 * 1024
constexpr int cSBLK = 88;                       // scan blocks

typedef __attribute__((ext_vector_type(8))) short bf16x8;
typedef __attribute__((ext_vector_type(4))) float f32x4;
typedef __attribute__((ext_vector_type(8))) unsigned short u16x8;

__device__ __forceinline__ unsigned short f2bf(float f) {
    unsigned u = __builtin_bit_cast(unsigned, f);
    u += 0x7FFF + ((u >> 16) & 1);            // RNE
    return (unsigned short)(u >> 16);
}
__device__ __forceinline__ float bf2f(unsigned short s) {
    unsigned u = ((unsigned)s) << 16;
    return __builtin_bit_cast(float, u);
}

#define GLOAD_LDS16(g, l) __builtin_amdgcn_global_load_lds(               \
    (const __attribute__((address_space(1))) void*)(g),                   \
    (__attribute__((address_space(3))) void*)(l), 16, 0, 0)

// ---------------------------------------------------------------------------
// setup2: fused {histogram | weight conv | xb conv}. offs pre-zeroed by memset.
// Flat ids: [0,901120) hist, [.. +65536) W1c, [.. +65536) W2c, [.. +1310720) xb.
// Total 2,342,912 = 9152 blocks x 256.
// ---------------------------------------------------------------------------
__global__ __launch_bounds__(256) void setup2_k(
    int* __restrict__ offs,
    const int* __restrict__ dst1, const int* __restrict__ dst2,
    const float* __restrict__ w1l, const float* __restrict__ w1r,
    const float* __restrict__ w2l, const float* __restrict__ w2r,
    unsigned short* __restrict__ W1c, unsigned short* __restrict__ W2c,
    const float* __restrict__ x, unsigned short* __restrict__ xb)
{
    int id = blockIdx.x * 256 + threadIdx.x;
    if (id < cEtot) {
        if (id < cE1) atomicAdd(&offs[dst1[id]], 1);
        else atomicAdd(&offs[cN1 + dst2[id - cE1]], 1);
        return;
    }
    id -= cEtot;
    if (id < 256 * 256) {
        int n = id >> 8, k = id & 255;
        float v = (k < 128) ? w1l[k * 256 + n] : w1r[(k - 128) * 256 + n];
        W1c[n * 256 + k] = f2bf(v);
        return;
    }
    id -= 256 * 256;
    if (id < 128 * 512) {
        int n = id >> 9, k = id & 511;
        float v = (k < 256) ? w2l[k * 128 + n] : w2r[(k - 256) * 128 + n];
        W2c[n * 512 + k] = f2bf(v);
        return;
    }
    id -= 128 * 512;
    {   // xb conversion: one vec8 per thread
        const float* p = x + (size_t)id * 8;
        float4 a = *reinterpret_cast<const float4*>(p);
        float4 b = *reinterpret_cast<const float4*>(p + 4);
        u16x8 o;
        o[0] = f2bf(a.x); o[1] = f2bf(a.y); o[2] = f2bf(a.z); o[3] = f2bf(a.w);
        o[4] = f2bf(b.x); o[5] = f2bf(b.y); o[6] = f2bf(b.z); o[7] = f2bf(b.w);
        reinterpret_cast<u16x8*>(xb)[id] = o;
    }
}

// ---------------------------------------------------------------------------
// Single-kernel exclusive scan over offs[90112], 88 blocks x 1024.
// Packed progress word per block: (value<<2)|state, state 1=aggregate 2=prefix.
// word[] pre-zeroed by memset. Layer-2 region gets -cE1 fixup.
// All 88 blocks are trivially co-resident (<< 256 CUs), so the spin is safe.
// ---------------------------------------------------------------------------
__global__ __launch_bounds__(1024) void scan_lb_k(
    int* __restrict__ a, unsigned* __restrict__ word)
{
    const int tid = threadIdx.x, bid = blockIdx.x;
    const int lane = tid & 63, wid = tid >> 6;
    const int g = bid * 1024 + tid;
    __shared__ int ws[16];
    __shared__ int aggs[cSBLK];
    __shared__ int pex[cSBLK];
    __shared__ int sh_excl;

    int v = a[g];
    int incl = v;
    #pragma unroll
    for (int off = 1; off < 64; off <<= 1) {
        int t = __shfl_up(incl, off, 64);
        if (lane >= off) incl += t;
    }
    if (lane == 63) ws[wid] = incl;
    __syncthreads();
    int wpre = 0;
    #pragma unroll
    for (int w = 0; w < 15; ++w) if (w < wid) wpre += ws[w];
    const int lexcl = wpre + incl - v;          // block-local exclusive
    if (tid == 0) {
        int tot = 0;
        #pragma unroll
        for (int w = 0; w < 16; ++w) tot += ws[w];
        __hip_atomic_store(&word[bid], ((unsigned)tot << 2) | 1u,
                           __ATOMIC_RELEASE, __HIP_MEMORY_SCOPE_AGENT);
    }

    if (bid == 0) {
        if (tid < cSBLK) {
            unsigned wv;
            do {
                wv = __hip_atomic_load(&word[tid], __ATOMIC_ACQUIRE,
                                       __HIP_MEMORY_SCOPE_AGENT);
            } while ((wv & 3u) == 0u);
            aggs[tid] = (int)(wv >> 2);
        }
        __syncthreads();
        if (tid == 0) {
            int run = 0;
            for (int i = 0; i < cSBLK; ++i) { pex[i] = run; run += aggs[i]; }
        }
        __syncthreads();
        if (tid < cSBLK)
            __hip_atomic_store(&word[tid], ((unsigned)pex[tid] << 2) | 2u,
                               __ATOMIC_RELEASE, __HIP_MEMORY_SCOPE_AGENT);
    }

    if (tid == 0) {
        unsigned wv;
        do {
            wv = __hip_atomic_load(&word[bid], __ATOMIC_ACQUIRE,
                                   __HIP_MEMORY_SCOPE_AGENT);
        } while ((wv & 3u) != 2u);
        sh_excl = (int)(wv >> 2);
    }
    __syncthreads();
    int r = sh_excl + lexcl;
    if (g >= cN1) r -= cE1;                     // layer-2 local offsets
    a[g] = r;
}

// ---------------------------------------------------------------------------
// fused CSR permute for both layers (cursor -> end offsets afterwards)
// ---------------------------------------------------------------------------
__global__ __launch_bounds__(256) void build_k(
    const int* __restrict__ src1, const int* __restrict__ dst1,
    const int* __restrict__ src2, const int* __restrict__ dst2,
    int* __restrict__ offs, int* __restrict__ eidx1, int* __restrict__ eidx2)
{
    int e = blockIdx.x * 256 + threadIdx.x;
    if (e < cE1) {
        int p = atomicAdd(&offs[dst1[e]], 1);
        eidx1[p] = src1[e];
    } else {
        int e2 = e - cE1;
        if (e2 < cE2) {
            int p = atomicAdd(&offs[cN1 + dst2[e2]], 1);
            eidx2[p] = src2[e2];
        }
    }
}

// ---------------------------------------------------------------------------
// Layer-1 aggregate: one wave per dst row, 16-lane group per edge.
// ---------------------------------------------------------------------------
__global__ __launch_bounds__(256) void agg1_k(
    const float* __restrict__ x, const int* __restrict__ cursor,
    const int* __restrict__ eidx, unsigned short* __restrict__ mean1)
{
    const int row = blockIdx.x * 4 + (threadIdx.x >> 6);
    const int lane = threadIdx.x & 63;
    const int g = lane >> 4, li = lane & 15;
    const int start = row ? cursor[row - 1] : 0;
    const int end = cursor[row];
    float acc[8] = {};
    for (int e = start + g; e < end; e += 4) {
        const int s = eidx[e];
        const float4* p = reinterpret_cast<const float4*>(x + (size_t)s * cDIN + li * 8);
        float4 a = p[0], b = p[1];
        acc[0] += a.x; acc[1] += a.y; acc[2] += a.z; acc[3] += a.w;
        acc[4] += b.x; acc[5] += b.y; acc[6] += b.z; acc[7] += b.w;
    }
    #pragma unroll
    for (int i = 0; i < 8; ++i) {
        acc[i] += __shfl_xor(acc[i], 16);
        acc[i] += __shfl_xor(acc[i], 32);
    }
    if (g == 0) {
        const float inv = 1.0f / fmaxf((float)(end - start), 1.0f);
        u16x8 o;
        #pragma unroll
        for (int i = 0; i < 8; ++i) o[i] = f2bf(acc[i] * inv);
        *reinterpret_cast<u16x8*>(mean1 + (size_t)row * cDIN + li * 8) = o;
    }
}

// ---------------------------------------------------------------------------
// Layer-2 aggregate: gather bf16 h rows; mean2 bf16.
// ---------------------------------------------------------------------------
__global__ __launch_bounds__(256) void agg2_k(
    const unsigned short* __restrict__ h, const int* __restrict__ cursor,
    const int* __restrict__ eidx, unsigned short* __restrict__ mean2)
{
    const int row = blockIdx.x * 4 + (threadIdx.x >> 6);
    const int lane = threadIdx.x & 63;
    const int g = lane >> 4, li = lane & 15;
    const int start = row ? cursor[row - 1] : 0;
    const int end = cursor[row];
    float acc[16] = {};
    for (int e = start + g; e < end; e += 4) {
        const int s = eidx[e];
        const u16x8* p = reinterpret_cast<const u16x8*>(h + (size_t)s * cDH + li * 16);
        u16x8 a = p[0], b = p[1];
        #pragma unroll
        for (int i = 0; i < 8; ++i) { acc[i] += bf2f(a[i]); acc[8 + i] += bf2f(b[i]); }
    }
    #pragma unroll
    for (int i = 0; i < 16; ++i) {
        acc[i] += __shfl_xor(acc[i], 16);
        acc[i] += __shfl_xor(acc[i], 32);
    }
    if (g == 0) {
        const float inv = 1.0f / fmaxf((float)(end - start), 1.0f);
        u16x8 o0, o1;
        #pragma unroll
        for (int i = 0; i < 8; ++i) { o0[i] = f2bf(acc[i] * inv); o1[i] = f2bf(acc[8 + i] * inv); }
        u16x8* q = reinterpret_cast<u16x8*>(mean2 + (size_t)row * cDH + li * 16);
        q[0] = o0; q[1] = o1;
    }
}

// ---------------------------------------------------------------------------
// Layer-1 GEMM, m97-style: global_load_lds(16B) staging, linear LDS,
// 128x128 tile, 4 waves 2x2, K=256 split as [mean1 | xb].   [verified R5/R6]
// ---------------------------------------------------------------------------
__global__ __launch_bounds__(256) void gemm1_k(
    const unsigned short* __restrict__ mean1,   // [N1][128] bf16
    const unsigned short* __restrict__ xb,      // [N1][128] bf16
    const unsigned short* __restrict__ W1c,     // [256][256] bf16 (n-major)
    const float* __restrict__ b1,
    unsigned short* __restrict__ h)             // [N1][256] bf16
{
    __shared__ unsigned short As[128 * 32];
    __shared__ unsigned short Bs[128 * 32];

    const int tid = threadIdx.x;
    const int l = tid & 63, w = tid >> 6;
    const int q = l >> 4, r16 = l & 15;
    const int wr0 = (w >> 1) * 64, wc0 = (w & 1) * 64;
    const int n0 = blockIdx.x * 128, row0 = blockIdx.y * 128;

    const int srow = w * 32 + (l >> 2);
    const int skoff = (l & 3) * 8;

    const f32x4 zero = {0.f, 0.f, 0.f, 0.f};
    f32x4 acc[4][4];
    #pragma unroll
    for (int m = 0; m < 4; ++m)
        #pragma unroll
        for (int n = 0; n < 4; ++n) acc[m][n] = zero;

    for (int k0 = 0; k0 < 256; k0 += 32) {
        const unsigned short* Asrc = (k0 < 128) ? mean1 : xb;
        const int kk = k0 & 127;
        __syncthreads();
        #pragma unroll
        for (int j = 0; j < 2; ++j) {
            const int r = srow + j * 16;
            GLOAD_LDS16(Asrc + (size_t)(row0 + r) * 128 + kk + skoff,
                        As + (w * 2 + j) * 512);
            GLOAD_LDS16(W1c + (size_t)(n0 + r) * 256 + k0 + skoff,
                        Bs + (w * 2 + j) * 512);
        }
        __syncthreads();
        bf16x8 af[4], bg[4];
        #pragma unroll
        for (int m = 0; m < 4; ++m)
            af[m] = *reinterpret_cast<const bf16x8*>(As + (wr0 + 16 * m + r16) * 32 + q * 8);
        #pragma unroll
        for (int n = 0; n < 4; ++n)
            bg[n] = *reinterpret_cast<const bf16x8*>(Bs + (wc0 + 16 * n + r16) * 32 + q * 8);
        #pragma unroll
        for (int m = 0; m < 4; ++m)
            #pragma unroll
            for (int n = 0; n < 4; ++n)
                acc[m][n] = __builtin_amdgcn_mfma_f32_16x16x32_bf16(af[m], bg[n], acc[m][n], 0, 0, 0);
    }

    #pragma unroll
    for (int n = 0; n < 4; ++n) {
        const int col = n0 + wc0 + 16 * n + r16;
        const float bv = b1[col];
        #pragma unroll
        for (int m = 0; m < 4; ++m) {
            #pragma unroll
            for (int j = 0; j < 4; ++j) {
                const int row = row0 + wr0 + 16 * m + 4 * q + j;
                h[(size_t)row * cDH + col] = f2bf(fmaxf(acc[m][n][j] + bv, 0.f));
            }
        }
    }
}

// ---------------------------------------------------------------------------
// Layer-2 GEMM: out = [mean2 | h] @ W2c^T + b2.  TM=32 -> 256 blocks.
// 4 waves 1x4 over cols (each 32x32), K=512.
// ---------------------------------------------------------------------------
__global__ __launch_bounds__(256) void gemm2_k(
    const unsigned short* __restrict__ mean2,   // [N2][256]
    const unsigned short* __restrict__ hd,      // [N2][256] (h top rows)
    const unsigned short* __restrict__ W2c,     // [128][512]
    const float* __restrict__ b2, float* __restrict__ out)
{
    constexpr int K = 512, KL = 256, N = 128, TM = 32;
    constexpr int LD = 40;
    __shared__ unsigned short As[TM * LD];
    __shared__ unsigned short Bs[128 * LD];

    const int tid = threadIdx.x;
    const int l = tid & 63, w = tid >> 6;
    const int q = l >> 4, r16 = l & 15;
    const int wc0 = w * 32;
    const int row0 = blockIdx.y * TM;

    const f32x4 zero = {0.f, 0.f, 0.f, 0.f};
    f32x4 acc[2][2];
    acc[0][0] = zero; acc[0][1] = zero; acc[1][0] = zero; acc[1][1] = zero;

    for (int k0 = 0; k0 < K; k0 += 32) {
        const bool left = (k0 < KL);
        const unsigned short* Asrc = left ? mean2 : hd;
        const int kk = k0 & (KL - 1);
        __syncthreads();
        if (tid < TM * 4) {                      // A tile: 32 rows x 4 slots
            int r = tid >> 2, o16 = tid & 3;
            bf16x8 av = *reinterpret_cast<const bf16x8*>(Asrc + (size_t)(row0 + r) * KL + kk + o16 * 8);
            *reinterpret_cast<bf16x8*>(As + r * LD + o16 * 8) = av;
        }
        #pragma unroll
        for (int c = 0; c < 2; ++c) {            // B tile: 128 rows -> 512 slots
            int z = tid + c * 256;
            int r = z >> 2, o16 = z & 3;
            bf16x8 bv = *reinterpret_cast<const bf16x8*>(W2c + (size_t)r * K + k0 + o16 * 8);
            *reinterpret_cast<bf16x8*>(Bs + r * LD + o16 * 8) = bv;
        }
        __syncthreads();
        bf16x8 af[2], bg[2];
        #pragma unroll
        for (int m = 0; m < 2; ++m)
            af[m] = *reinterpret_cast<const bf16x8*>(As + (16 * m + r16) * LD + q * 8);
        #pragma unroll
        for (int n = 0; n < 2; ++n)
            bg[n] = *reinterpret_cast<const bf16x8*>(Bs + (wc0 + 16 * n + r16) * LD + q * 8);
        #pragma unroll
        for (int m = 0; m < 2; ++m)
            #pragma unroll
            for (int n = 0; n < 2; ++n)
                acc[m][n] = __builtin_amdgcn_mfma_f32_16x16x32_bf16(af[m], bg[n], acc[m][n], 0, 0, 0);
    }

    #pragma unroll
    for (int n = 0; n < 2; ++n) {
        const int col = wc0 + 16 * n + r16;
        const float bv = b2[col];
        #pragma unroll
        for (int m = 0; m < 2; ++m) {
            #pragma unroll
            for (int j = 0; j < 4; ++j) {
                const int row = row0 + 16 * m + 4 * q + j;
                out[(size_t)row * N + col] = acc[m][n][j] + bv;
            }
        }
    }
}

// ---------------------------------------------------------------------------
extern "C" void kernel_launch(void* const* d_in, const int* in_sizes, int n_in,
                              void* d_out, int out_size, void* d_ws, size_t ws_size,
                              hipStream_t stream)
{
    const float* x    = (const float*)d_in[0];
    const int*   src1 = (const int*)d_in[1];
    const int*   dst1 = (const int*)d_in[2];
    const int*   src2 = (const int*)d_in[3];
    const int*   dst2 = (const int*)d_in[4];
    const float* w1l  = (const float*)d_in[7];
    const float* b1   = (const float*)d_in[8];
    const float* w1r  = (const float*)d_in[9];
    const float* w2l  = (const float*)d_in[10];
    const float* b2   = (const float*)d_in[11];
    const float* w2r  = (const float*)d_in[12];
    float* out = (float*)d_out;

    // Workspace (~92.4 MB):
    unsigned short* mean1 = (unsigned short*)d_ws;        // [81920][128]
    unsigned short* h     = mean1 + (size_t)cN1 * cDIN;   // [81920][256]
    unsigned short* mean2 = h + (size_t)cN1 * cDH;        // [8192][256]
    unsigned short* W1c   = mean2 + (size_t)cN2 * cDH;    // [256][256]
    unsigned short* W2c   = W1c + 256 * 256;              // [128][512]
    unsigned short* xb    = W2c + 128 * 512;              // [81920][128]
    int* offs  = (int*)(xb + (size_t)cN1 * cDIN);         // [90112]
    unsigned* word = (unsigned*)(offs + cNOFF);           // [88]
    int* eidx1 = (int*)(word + cSBLK);                    // [819200]
    int* eidx2 = eidx1 + cE1;                             // [81920]

    // 1. zero offs + scan progress words (360 KB)
    hipMemsetAsync(offs, 0, (size_t)(cNOFF + cSBLK) * sizeof(int), stream);
    // 2. fused setup: hist | W conv | xb conv   (9152 blocks)
    {
        int total = cEtot + 256 * 256 + 128 * 512 + cN1 * cDIN / 8;  // 2,342,912
        setup2_k<<<total / 256, 256, 0, stream>>>(offs, dst1, dst2,
                                                  w1l, w1r, w2l, w2r,
                                                  W1c, W2c, x, xb);
    }
    // 3. single-kernel exclusive scan
    scan_lb_k<<<cSBLK, 1024, 0, stream>>>(offs, word);
    // 4. CSR permute
    build_k<<<(cE1 + cE2) / 256, 256, 0, stream>>>(src1, dst1, src2, dst2, offs, eidx1, eidx2);
    // 5. layer-1 aggregate
    agg1_k<<<cN1 / 4, 256, 0, stream>>>(x, offs, eidx1, mean1);
    // 6. layer-1 GEMM
    gemm1_k<<<dim3(2, cN1 / 128), 256, 0, stream>>>(mean1, xb, W1c, b1, h);
    // 7. layer-2 aggregate
    agg2_k<<<cN2 / 4, 256, 0, stream>>>(h, offs + cN1, eidx2, mean2);
    // 8. layer-2 GEMM
    gemm2_k<<<dim3(1, cN2 / 32), 256, 0, stream>>>(mean2, h, W2c, b2, out);
}